// Round 8
// baseline (201.459 us; speedup 1.0000x reference)
//
#include <hip/hip_runtime.h>
#include <math.h>

#define B_  2
#define Q_  2048
#define CQ_ 512
#define H_  8
#define D_  64
#define M_  (B_*Q_)   // 4096
#define L2E 1.44269504088896f

typedef __bf16 bf16;
typedef __bf16 bf16x4 __attribute__((ext_vector_type(4)));
typedef __bf16 bf16x8 __attribute__((ext_vector_type(8)));
typedef float  f32x4  __attribute__((ext_vector_type(4)));
typedef float  f32x16 __attribute__((ext_vector_type(16)));

// async global->LDS, 16 bytes per lane; lds dest = wave-uniform base + lane*16
__device__ __forceinline__ void gl_lds16(const bf16* g, bf16* l) {
    __builtin_amdgcn_global_load_lds(
        (const __attribute__((address_space(1))) unsigned int*)g,
        (__attribute__((address_space(3))) unsigned int*)l, 16, 0, 0);
}

// ---------------------------------------------------------------------------
// fp32 -> bf16 conversion
// ---------------------------------------------------------------------------
#define S0 (4096*512)    // q_x
#define S1 (1536*512)    // w_qkv
#define S2 (512*512)     // w_g
#define S3 (512*512)     // w_o
__global__ __launch_bounds__(256)
void convert_kernel(const float* __restrict__ qx, const float* __restrict__ wqkv,
                    const float* __restrict__ wg, const float* __restrict__ wo,
                    bf16* __restrict__ qxb, bf16* __restrict__ wcat, bf16* __restrict__ wob)
{
    const long long t = (long long)blockIdx.x * 256 + threadIdx.x;
    const long long e = t * 8;
    const float* src; bf16* dst;
    if (e < S0)                { src = qx + e;                  dst = qxb + e; }
    else if (e < S0 + S1)      { src = wqkv + (e - S0);         dst = wcat + (e - S0); }
    else if (e < S0 + S1 + S2) { src = wg + (e - S0 - S1);      dst = wcat + S1 + (e - S0 - S1); }
    else                       { src = wo + (e - S0 - S1 - S2); dst = wob + (e - S0 - S1 - S2); }
    const float4 a = *(const float4*)(src);
    const float4 b = *(const float4*)(src + 4);
    bf16x8 v;
    v[0] = (bf16)a.x; v[1] = (bf16)a.y; v[2] = (bf16)a.z; v[3] = (bf16)a.w;
    v[4] = (bf16)b.x; v[5] = (bf16)b.y; v[6] = (bf16)b.z; v[7] = (bf16)b.w;
    *(bf16x8*)dst = v;
}

// ---------------------------------------------------------------------------
// bf16 MFMA GEMM: C[M,N] = A[M,512] * W[N,512]^T, K=512, BK=32.
// All parts except V compute C^T (swapped mfma operands) -> vector stores.
// EPI 0: n<512 q | <1024 k(frag) | <1536 v(frag) | else gate.  EPI 1: +b_o.
// ---------------------------------------------------------------------------
template<int BM, int BN, int EPI>
__global__ __launch_bounds__(256)
void gemm_bf16(const bf16* __restrict__ A, const bf16* __restrict__ W,
               const float* __restrict__ bvec, float* __restrict__ fout,
               bf16* __restrict__ qb, bf16* __restrict__ kb, bf16* __restrict__ vb,
               bf16* __restrict__ gb)
{
    constexpr int MI = BM / 32, NJ = BN / 32;
    __shared__ __align__(16) bf16 As[BM * 32];
    __shared__ __align__(16) bf16 Bs[BN * 32];

    const int t = threadIdx.x;
    const int w = t >> 6, lane = t & 63;
    const int l15 = lane & 15, quad = lane >> 4;
    const int wm = w & 1, wn = w >> 1;
    const int bm = blockIdx.x * BM;
    const int bn = blockIdx.y * BN;
    const bool swapped = (EPI == 1) || ((bn >> 9) != 2);

    f32x4 acc[MI][NJ] = {};

    const int rr = t >> 2;
    const int cc = (t & 3) * 8;

    for (int k0 = 0; k0 < 512; k0 += 32) {
        #pragma unroll
        for (int i = 0; i < BM / 64; ++i)
            gl_lds16(A + (size_t)(bm + i * 64 + rr) * 512 + k0 + cc,
                     As + (i * 64 + w * 16) * 32);
        #pragma unroll
        for (int i = 0; i < BN / 64; ++i)
            gl_lds16(W + (size_t)(bn + i * 64 + rr) * 512 + k0 + cc,
                     Bs + (i * 64 + w * 16) * 32);
        __asm__ volatile("s_waitcnt vmcnt(0)" ::: "memory");
        __syncthreads();

        bf16x8 af[MI], bfr[NJ];
        #pragma unroll
        for (int i = 0; i < MI; ++i)
            af[i] = *(const bf16x8*)(As + (wm * (BM / 2) + i * 16 + l15) * 32 + quad * 8);
        #pragma unroll
        for (int j = 0; j < NJ; ++j)
            bfr[j] = *(const bf16x8*)(Bs + (wn * (BN / 2) + j * 16 + l15) * 32 + quad * 8);
        if (swapped) {
            #pragma unroll
            for (int i = 0; i < MI; ++i)
                #pragma unroll
                for (int j = 0; j < NJ; ++j)
                    acc[i][j] = __builtin_amdgcn_mfma_f32_16x16x32_bf16(bfr[j], af[i], acc[i][j], 0, 0, 0);
        } else {
            #pragma unroll
            for (int i = 0; i < MI; ++i)
                #pragma unroll
                for (int j = 0; j < NJ; ++j)
                    acc[i][j] = __builtin_amdgcn_mfma_f32_16x16x32_bf16(af[i], bfr[j], acc[i][j], 0, 0, 0);
        }
        __syncthreads();
    }

    if (swapped) {
        #pragma unroll
        for (int i = 0; i < MI; ++i) {
            const int m = bm + wm * (BM / 2) + i * 16 + l15;
            const int b = m >> 11, qq = m & 2047;
            #pragma unroll
            for (int j = 0; j < NJ; ++j) {
                const int n0 = bn + wn * (BN / 2) + j * 16 + quad * 4;
                const f32x4 cv = acc[i][j];
                if constexpr (EPI == 1) {
                    float4 st;
                    st.x = cv[0] + bvec[n0 + 0];
                    st.y = cv[1] + bvec[n0 + 1];
                    st.z = cv[2] + bvec[n0 + 2];
                    st.w = cv[3] + bvec[n0 + 3];
                    *(float4*)(fout + (size_t)m * 512 + n0) = st;
                } else {
                    const int part = n0 >> 9;
                    if (part == 0) {
                        const int h = (n0 >> 6) & 7, d0 = n0 & 63;
                        bf16x4 q4;
                        #pragma unroll
                        for (int r = 0; r < 4; ++r) q4[r] = (bf16)(cv[r] * (0.125f * L2E));
                        *(bf16x4*)(qb + (size_t)(b * H_ + h) * (Q_ * D_) + (size_t)qq * 64 + d0) = q4;
                    } else if (part == 1) {
                        const int h = (n0 >> 6) & 7, d0 = n0 & 63;
                        const size_t off = (size_t)(b * H_ + h) * (Q_ * D_)
                            + (qq >> 6) * 4096 + ((qq >> 5) & 1) * 2048
                            + (d0 >> 4) * 512 + ((d0 >> 3) & 1) * 256
                            + (qq & 31) * 8 + (d0 & 7);
                        bf16x4 k4;
                        #pragma unroll
                        for (int r = 0; r < 4; ++r) k4[r] = (bf16)cv[r];
                        *(bf16x4*)(kb + off) = k4;
                    } else {
                        const int gcol = n0 & 511;
                        const float4 bv4 = *(const float4*)(bvec + gcol);
                        bf16x4 g4;
                        g4[0] = (bf16)(1.f / (1.f + __expf(-(cv[0] + bv4.x))));
                        g4[1] = (bf16)(1.f / (1.f + __expf(-(cv[1] + bv4.y))));
                        g4[2] = (bf16)(1.f / (1.f + __expf(-(cv[2] + bv4.z))));
                        g4[3] = (bf16)(1.f / (1.f + __expf(-(cv[3] + bv4.w))));
                        *(bf16x4*)(gb + (size_t)m * 512 + gcol) = g4;
                    }
                }
            }
        }
    } else {
        // V part, normal orientation: lane holds 4 consecutive qq for fixed d
        #pragma unroll
        for (int i = 0; i < MI; ++i) {
            const int m0 = bm + wm * (BM / 2) + i * 16 + quad * 4;
            const int b = m0 >> 11, qq0 = m0 & 2047;
            #pragma unroll
            for (int j = 0; j < NJ; ++j) {
                const int n = bn + wn * (BN / 2) + j * 16 + l15;
                const int h = (n >> 6) & 7, d = n & 63;
                const size_t off = (size_t)(b * H_ + h) * (Q_ * D_)
                    + (qq0 >> 6) * 4096 + (d >> 5) * 2048
                    + ((qq0 & 63) >> 4) * 512 + ((qq0 >> 3) & 1) * 256
                    + (d & 31) * 8 + (qq0 & 7);
                bf16x4 v4;
                #pragma unroll
                for (int r = 0; r < 4; ++r) v4[r] = (bf16)acc[i][j][r];
                *(bf16x4*)(vb + off) = v4;
            }
        }
    }
}

// ---------------------------------------------------------------------------
// Split-K MFMA flash attention (32x32x16, transposed dataflow S^T/O^T).
// Grid (16 bh, 16 qt, 2 ks) = 512 blocks -> 2/CU, even 16-step slabs.
// K/V staged to LDS via REGISTER relay (coalesced float4, conflict-free
// 16B-stride LDS writes) -- measured 2x faster per block-step than
// global_load_lds staging (R3 vs R5/6/7: 2.1k vs 4.1k cyc/block-step),
// because load latency hides across the whole step body and there is no
// in-loop vmcnt(0) drain. Double-buffered; one barrier per step.
// NO max-subtraction (scores ~N(0,1), exp2-safe in fp32): partials are
// plain (sum pV, sum p); merge = add + divide.
// ---------------------------------------------------------------------------
__global__ __launch_bounds__(256, 2)
void attn_part(const bf16* __restrict__ qb, const bf16* __restrict__ kf,
               const bf16* __restrict__ vf, const float* __restrict__ bias,
               bf16* __restrict__ po, float* __restrict__ lsum)
{
    __shared__ __align__(16) bf16 Ks[2][4096];
    __shared__ __align__(16) bf16 Vs[2][4096];
    __shared__ __align__(16) bf16 Ps[4][32 * 72];

    const int tid  = threadIdx.x;
    const int wv   = tid >> 6, lane = tid & 63;
    const int l31  = lane & 31, b5 = lane >> 5;
    const int x    = blockIdx.x;
    const int bh   = ((x & 7) << 1) | (x >> 3);   // XCD gets same-b head pair
    const int b    = bh >> 3;
    const int qg   = blockIdx.y * 128 + wv * 32 + l31;
    const int ks   = blockIdx.z;

    const bf16* qp = qb + ((size_t)bh * Q_ + qg) * D_;
    bf16x8 bq[4];
    #pragma unroll
    for (int c = 0; c < 4; ++c)
        bq[c] = *(const bf16x8*)(qp + c * 16 + b5 * 8);

    f32x16 acc[2] = {};
    float l_loc = 0.f;

    const bf16*  kfb  = kf + (size_t)bh * (Q_ * D_) + (size_t)ks * 16 * 4096;
    const bf16*  vfb  = vf + (size_t)bh * (Q_ * D_) + (size_t)ks * 16 * 4096;
    const float* brow = bias + ((size_t)b * Q_ + qg) * Q_ + ks * 1024;

    f32x4 bcur[8], bnxt[8];
    float4 kr[2], vr[2];
    const int so = tid * 8;                  // 16B per thread per 4KB chunk

    // ---- prologue: stage tile 0 via registers, load bias 0 ----
    #pragma unroll
    for (int c = 0; c < 2; ++c) {
        kr[c] = *(const float4*)(kfb + c * 2048 + so);
        vr[c] = *(const float4*)(vfb + c * 2048 + so);
    }
    #pragma unroll
    for (int i = 0; i < 8; ++i)
        bcur[i] = *(const f32x4*)(brow + (i >> 2) * 32 + (i & 3) * 8 + b5 * 4);
    #pragma unroll
    for (int c = 0; c < 2; ++c) {
        *(float4*)(Ks[0] + c * 2048 + so) = kr[c];
        *(float4*)(Vs[0] + c * 2048 + so) = vr[c];
    }
    __syncthreads();

    bf16* pw = Ps[wv] + l31 * 72;

    int cur = 0;
    #pragma unroll 1
    for (int t = 0; t < 16; ++t) {
        // issue next tile's K/V/bias loads into registers (latency hidden
        // by this step's compute; compiler places the waitcnt late)
        if (t < 15) {
            const size_t off = (size_t)(t + 1) * 4096;
            #pragma unroll
            for (int c = 0; c < 2; ++c) {
                kr[c] = *(const float4*)(kfb + off + c * 2048 + so);
                vr[c] = *(const float4*)(vfb + off + c * 2048 + so);
            }
            const int k0n = (t + 1) * 64;
            #pragma unroll
            for (int i = 0; i < 8; ++i)
                bnxt[i] = *(const f32x4*)(brow + k0n + (i >> 2) * 32 + (i & 3) * 8 + b5 * 4);
        }

        // ---- scores S^T ----
        const bf16* Kc = Ks[cur];
        f32x16 sv[2] = {};
        #pragma unroll
        for (int kg = 0; kg < 2; ++kg)
            #pragma unroll
            for (int c = 0; c < 4; ++c) {
                const bf16x8 ak = *(const bf16x8*)(Kc + kg * 2048 + c * 512 + lane * 8);
                sv[kg] = __builtin_amdgcn_mfma_f32_32x32x16_bf16(ak, bq[c], sv[kg], 0, 0, 0);
            }

        // ---- p = exp2(score + bias), no max-subtract; accumulate local l ----
        float sc[2][16];
        float rsum = 0.f;
        #pragma unroll
        for (int kg = 0; kg < 2; ++kg)
            #pragma unroll
            for (int r = 0; r < 16; ++r) {
                sc[kg][r] = __builtin_amdgcn_exp2f(
                    fmaf(bcur[kg * 4 + (r >> 2)][r & 3], L2E, sv[kg][r]));
                rsum += sc[kg][r];
            }
        l_loc += rsum;

        // ---- P^T -> per-wave LDS [q][key] (8x b64) ----
        #pragma unroll
        for (int kg = 0; kg < 2; ++kg)
            #pragma unroll
            for (int gi = 0; gi < 4; ++gi) {
                bf16x4 p4;
                p4[0] = (bf16)sc[kg][gi * 4 + 0];
                p4[1] = (bf16)sc[kg][gi * 4 + 1];
                p4[2] = (bf16)sc[kg][gi * 4 + 2];
                p4[3] = (bf16)sc[kg][gi * 4 + 3];
                *(bf16x4*)(pw + kg * 32 + gi * 8 + b5 * 4) = p4;
            }
        __asm__ volatile("s_waitcnt lgkmcnt(0)" ::: "memory");

        // ---- PV: O^T += V^T * P^T ----
        const bf16* Vc = Vs[cur];
        #pragma unroll
        for (int c4 = 0; c4 < 4; ++c4) {
            const bf16x8 bp = *(const bf16x8*)(pw + c4 * 16 + b5 * 8);
            #pragma unroll
            for (int dg = 0; dg < 2; ++dg) {
                const bf16x8 av = *(const bf16x8*)(Vc + dg * 2048 + c4 * 512 + lane * 8);
                acc[dg] = __builtin_amdgcn_mfma_f32_32x32x16_bf16(av, bp, acc[dg], 0, 0, 0);
            }
        }

        // ---- commit prefetched tile to the other LDS buffer ----
        if (t < 15) {
            #pragma unroll
            for (int c = 0; c < 2; ++c) {
                *(float4*)(Ks[cur ^ 1] + c * 2048 + so) = kr[c];
                *(float4*)(Vs[cur ^ 1] + c * 2048 + so) = vr[c];
            }
            #pragma unroll
            for (int i = 0; i < 8; ++i) bcur[i] = bnxt[i];
        }
        __syncthreads();
        cur ^= 1;
    }

    // ---- partial epilogue: UNnormalized O (bf16) + row-sum l ----
    const float l_run = l_loc + __shfl_xor(l_loc, 32, 64);
    const size_t pbase = ((size_t)(ks * 16 + bh) * Q_ + qg) * 64;
    #pragma unroll
    for (int dg = 0; dg < 2; ++dg)
        #pragma unroll
        for (int gi = 0; gi < 4; ++gi) {
            const int d0 = dg * 32 + gi * 8 + b5 * 4;
            bf16x4 ov;
            #pragma unroll
            for (int r = 0; r < 4; ++r)
                ov[r] = (bf16)acc[dg][gi * 4 + r];
            *(bf16x4*)(po + pbase + d0) = ov;
        }
    if (b5 == 0)
        lsum[(size_t)(ks * 16 + bh) * Q_ + qg] = l_run;
}

// ---------------------------------------------------------------------------
// Merge 2 split-K partials, apply gate; og may alias g (in-place, elementwise).
// ---------------------------------------------------------------------------
__global__ __launch_bounds__(256)
void merge_kernel(const bf16* __restrict__ po, const float* __restrict__ lsum,
                  const bf16* g, bf16* og)
{
    const int gid = blockIdx.x * 256 + threadIdx.x;
    const int row = gid >> 3;             // bh*2048 + qg
    const int d8  = (gid & 7) * 8;
    const int bh  = row >> 11, qg = row & 2047;
    const int b   = bh >> 3, h = bh & 7;

    const float inv = 1.f / (lsum[row] + lsum[16 * Q_ + row]);

    const bf16x8 o0 = *(const bf16x8*)(po + (size_t)row * 64 + d8);
    const bf16x8 o1 = *(const bf16x8*)(po + (size_t)16 * Q_ * 64 + (size_t)row * 64 + d8);
    const size_t obase = ((size_t)(b * Q_ + qg)) * 512 + h * 64 + d8;
    const bf16x8 gv = *(const bf16x8*)(g + obase);
    bf16x8 ov;
    #pragma unroll
    for (int r = 0; r < 8; ++r)
        ov[r] = (bf16)(((float)o0[r] + (float)o1[r]) * inv * (float)gv[r]);
    *(bf16x8*)(og + obase) = ov;
}

// ---------------------------------------------------------------------------
extern "C" void kernel_launch(void* const* d_in, const int* in_sizes, int n_in,
                              void* d_out, int out_size, void* d_ws, size_t ws_size,
                              hipStream_t stream)
{
    const float* q_x   = (const float*)d_in[0];
    const float* bias  = (const float*)d_in[2];
    const float* w_qkv = (const float*)d_in[3];
    const float* w_o   = (const float*)d_in[4];
    const float* b_o   = (const float*)d_in[5];
    const float* w_g   = (const float*)d_in[6];
    const float* b_g   = (const float*)d_in[7];
    float* out = (float*)d_out;

    char* ws = (char*)d_ws;
    bf16*  po   = (bf16*)(ws);                     // 8 MB partials (overlays qxb/wcat)
    bf16*  qxb  = (bf16*)(ws);                     // 4 MB  (dead before attn)
    bf16*  wcat = (bf16*)(ws + (4u  << 20));       // 2 MB  (dead before attn)
    bf16*  qb   = (bf16*)(ws + (12u << 20));       // 4 MB
    bf16*  kb   = (bf16*)(ws + (16u << 20));       // 4 MB  K frag-ordered
    bf16*  vb   = (bf16*)(ws + (20u << 20));       // 4 MB  V^T frag-ordered
    bf16*  gb   = (bf16*)(ws + (24u << 20));       // 4 MB  gate -> gated O (in-place)
    bf16*  wob  = (bf16*)(ws + (28u << 20));       // 0.5 MB
    float* lsum = (float*)(ws + (28u << 20) + (1u << 19));  // 256 KB

    // 1) fp32 -> bf16 conversions
    convert_kernel<<<(S0 + S1 + S2 + S3) / (256 * 8), 256, 0, stream>>>(
        q_x, w_qkv, w_g, w_o, qxb, wcat, wob);
    // 2) fused QKV + gate projection (bf16 MFMA), BN=64 -> 1024 blocks
    gemm_bf16<128, 64, 0><<<dim3(32, 32), 256, 0, stream>>>(
        qxb, wcat, b_g, nullptr, qb, kb, vb, gb);
    // 3) split-K(2) flash attention partials, register-relay staging
    attn_part<<<dim3(B_ * H_, Q_ / 128, 2), 256, 0, stream>>>(qb, kb, vb, bias, po, lsum);
    // 4) merge partials + gate (in-place into gb)
    merge_kernel<<<(16 * Q_ * 8) / 256, 256, 0, stream>>>(po, lsum, gb, gb);
    // 5) output projection + b_o, 64x64 -> 512 blocks
    gemm_bf16<64, 64, 1><<<dim3(64, 8), 256, 0, stream>>>(
        gb, wob, b_o, out, nullptr, nullptr, nullptr, nullptr);
}

// Round 9
// 184.728 us; speedup vs baseline: 1.0906x; 1.0906x over previous
//
#include <hip/hip_runtime.h>
#include <math.h>

#define B_  2
#define Q_  2048
#define CQ_ 512
#define H_  8
#define D_  64
#define M_  (B_*Q_)   // 4096
#define L2E 1.44269504088896f

typedef __bf16 bf16;
typedef __bf16 bf16x4 __attribute__((ext_vector_type(4)));
typedef __bf16 bf16x8 __attribute__((ext_vector_type(8)));
typedef float  f32x4  __attribute__((ext_vector_type(4)));
typedef float  f32x16 __attribute__((ext_vector_type(16)));

// async global->LDS, 16 bytes per lane; lds dest = wave-uniform base + lane*16
__device__ __forceinline__ void gl_lds16(const bf16* g, bf16* l) {
    __builtin_amdgcn_global_load_lds(
        (const __attribute__((address_space(1))) unsigned int*)g,
        (__attribute__((address_space(3))) unsigned int*)l, 16, 0, 0);
}

// ---------------------------------------------------------------------------
// fp32 -> bf16 conversion INTO K-PANEL-PACKED layout:
//   pack_off(row, k; R) = (k>>5) * (R*32) + row*32 + (k&31)
// This is exactly the LDS image the GEMM stages, so every staging
// global_load_lds reads 1 KB fully CONTIGUOUS (no 64B gather).
// ---------------------------------------------------------------------------
#define S0 (4096*512)    // q_x
#define S1 (1536*512)    // w_qkv
#define S2 (512*512)     // w_g
#define S3 (512*512)     // w_o
__global__ __launch_bounds__(256)
void convert_kernel(const float* __restrict__ qx, const float* __restrict__ wqkv,
                    const float* __restrict__ wg, const float* __restrict__ wo,
                    bf16* __restrict__ qxb, bf16* __restrict__ wcat, bf16* __restrict__ wob)
{
    const long long t = (long long)blockIdx.x * 256 + threadIdx.x;
    const long long e = t * 8;
    const float* src; bf16* dst;
    if (e < S0) {
        const int m = (int)(e >> 9), k = (int)(e & 511);
        src = qx + e;
        dst = qxb + (size_t)(k >> 5) * (4096 * 32) + (size_t)m * 32 + (k & 31);
    } else if (e < S0 + S1) {
        const long long e2 = e - S0;
        const int n = (int)(e2 >> 9), k = (int)(e2 & 511);
        src = wqkv + e2;
        dst = wcat + (size_t)(k >> 5) * (2048 * 32) + (size_t)n * 32 + (k & 31);
    } else if (e < S0 + S1 + S2) {
        const long long e2 = e - S0 - S1;
        const int n = 1536 + (int)(e2 >> 9), k = (int)(e2 & 511);
        src = wg + e2;
        dst = wcat + (size_t)(k >> 5) * (2048 * 32) + (size_t)n * 32 + (k & 31);
    } else {
        const long long e2 = e - S0 - S1 - S2;
        const int n = (int)(e2 >> 9), k = (int)(e2 & 511);
        src = wo + e2;
        dst = wob + (size_t)(k >> 5) * (512 * 32) + (size_t)n * 32 + (k & 31);
    }
    const float4 a = *(const float4*)(src);
    const float4 b = *(const float4*)(src + 4);
    bf16x8 v;
    v[0] = (bf16)a.x; v[1] = (bf16)a.y; v[2] = (bf16)a.z; v[3] = (bf16)a.w;
    v[4] = (bf16)b.x; v[5] = (bf16)b.y; v[6] = (bf16)b.z; v[7] = (bf16)b.w;
    *(bf16x8*)dst = v;
}

// ---------------------------------------------------------------------------
// bf16 MFMA GEMM on PACKED operands: C[M,N] = A[M,512] * W[N,512]^T, BK=32.
// A rows = 4096 (always); W rows = WNR (template). Staging: each
// global_load_lds covers 1 KB contiguous (pack layout == LDS image).
// All parts except V compute C^T (swapped operands) -> vector stores.
// EPI 0: n<512 q | <1024 k(frag) | <1536 v(frag) | else gate.  EPI 1: +b_o.
// ---------------------------------------------------------------------------
template<int BM, int BN, int EPI, int WNR>
__global__ __launch_bounds__(256)
void gemm_bf16(const bf16* __restrict__ A, const bf16* __restrict__ W,
               const float* __restrict__ bvec, float* __restrict__ fout,
               bf16* __restrict__ qb, bf16* __restrict__ kb, bf16* __restrict__ vb,
               bf16* __restrict__ gb)
{
    constexpr int MI = BM / 32, NJ = BN / 32;
    constexpr int APARTS = BM / 16, BPARTS = BN / 16, NPARTS = APARTS + BPARTS;
    __shared__ __align__(16) bf16 As[BM * 32];
    __shared__ __align__(16) bf16 Bs[BN * 32];

    const int t = threadIdx.x;
    const int w = t >> 6, lane = t & 63;
    const int l15 = lane & 15, quad = lane >> 4;
    const int wm = w & 1, wn = w >> 1;
    const int bm = blockIdx.x * BM;
    const int bn = blockIdx.y * BN;
    const bool swapped = (EPI == 1) || ((bn >> 9) != 2);

    f32x4 acc[MI][NJ] = {};

    for (int k0 = 0; k0 < 512; k0 += 32) {
        const size_t apan = (size_t)(k0 >> 5) * (4096 * 32) + (size_t)bm * 32;
        const size_t bpan = (size_t)(k0 >> 5) * (WNR * 32) + (size_t)bn * 32;
        #pragma unroll
        for (int idx = 0; idx < NPARTS / 4; ++idx) {
            const int p = idx * 4 + w;
            if (p < APARTS)
                gl_lds16(A + apan + p * 512 + lane * 8, As + p * 512);
            else
                gl_lds16(W + bpan + (p - APARTS) * 512 + lane * 8, Bs + (p - APARTS) * 512);
        }
        __asm__ volatile("s_waitcnt vmcnt(0)" ::: "memory");
        __syncthreads();

        bf16x8 af[MI], bfr[NJ];
        #pragma unroll
        for (int i = 0; i < MI; ++i)
            af[i] = *(const bf16x8*)(As + (wm * (BM / 2) + i * 16 + l15) * 32 + quad * 8);
        #pragma unroll
        for (int j = 0; j < NJ; ++j)
            bfr[j] = *(const bf16x8*)(Bs + (wn * (BN / 2) + j * 16 + l15) * 32 + quad * 8);
        if (swapped) {
            #pragma unroll
            for (int i = 0; i < MI; ++i)
                #pragma unroll
                for (int j = 0; j < NJ; ++j)
                    acc[i][j] = __builtin_amdgcn_mfma_f32_16x16x32_bf16(bfr[j], af[i], acc[i][j], 0, 0, 0);
        } else {
            #pragma unroll
            for (int i = 0; i < MI; ++i)
                #pragma unroll
                for (int j = 0; j < NJ; ++j)
                    acc[i][j] = __builtin_amdgcn_mfma_f32_16x16x32_bf16(af[i], bfr[j], acc[i][j], 0, 0, 0);
        }
        __syncthreads();
    }

    if (swapped) {
        #pragma unroll
        for (int i = 0; i < MI; ++i) {
            const int m = bm + wm * (BM / 2) + i * 16 + l15;
            const int b = m >> 11, qq = m & 2047;
            #pragma unroll
            for (int j = 0; j < NJ; ++j) {
                const int n0 = bn + wn * (BN / 2) + j * 16 + quad * 4;
                const f32x4 cv = acc[i][j];
                if constexpr (EPI == 1) {
                    float4 st;
                    st.x = cv[0] + bvec[n0 + 0];
                    st.y = cv[1] + bvec[n0 + 1];
                    st.z = cv[2] + bvec[n0 + 2];
                    st.w = cv[3] + bvec[n0 + 3];
                    *(float4*)(fout + (size_t)m * 512 + n0) = st;
                } else {
                    const int part = n0 >> 9;
                    if (part == 0) {
                        const int h = (n0 >> 6) & 7, d0 = n0 & 63;
                        bf16x4 q4;
                        #pragma unroll
                        for (int r = 0; r < 4; ++r) q4[r] = (bf16)(cv[r] * (0.125f * L2E));
                        *(bf16x4*)(qb + (size_t)(b * H_ + h) * (Q_ * D_) + (size_t)qq * 64 + d0) = q4;
                    } else if (part == 1) {
                        const int h = (n0 >> 6) & 7, d0 = n0 & 63;
                        const size_t off = (size_t)(b * H_ + h) * (Q_ * D_)
                            + (qq >> 6) * 4096 + ((qq >> 5) & 1) * 2048
                            + (d0 >> 4) * 512 + ((d0 >> 3) & 1) * 256
                            + (qq & 31) * 8 + (d0 & 7);
                        bf16x4 k4;
                        #pragma unroll
                        for (int r = 0; r < 4; ++r) k4[r] = (bf16)cv[r];
                        *(bf16x4*)(kb + off) = k4;
                    } else {
                        const int gcol = n0 & 511;
                        const float4 bv4 = *(const float4*)(bvec + gcol);
                        bf16x4 g4;
                        g4[0] = (bf16)(1.f / (1.f + __expf(-(cv[0] + bv4.x))));
                        g4[1] = (bf16)(1.f / (1.f + __expf(-(cv[1] + bv4.y))));
                        g4[2] = (bf16)(1.f / (1.f + __expf(-(cv[2] + bv4.z))));
                        g4[3] = (bf16)(1.f / (1.f + __expf(-(cv[3] + bv4.w))));
                        *(bf16x4*)(gb + (size_t)m * 512 + gcol) = g4;
                    }
                }
            }
        }
    } else {
        // V part, normal orientation: lane holds 4 consecutive qq for fixed d
        #pragma unroll
        for (int i = 0; i < MI; ++i) {
            const int m0 = bm + wm * (BM / 2) + i * 16 + quad * 4;
            const int b = m0 >> 11, qq0 = m0 & 2047;
            #pragma unroll
            for (int j = 0; j < NJ; ++j) {
                const int n = bn + wn * (BN / 2) + j * 16 + l15;
                const int h = (n >> 6) & 7, d = n & 63;
                const size_t off = (size_t)(b * H_ + h) * (Q_ * D_)
                    + (qq0 >> 6) * 4096 + (d >> 5) * 2048
                    + ((qq0 & 63) >> 4) * 512 + ((qq0 >> 3) & 1) * 256
                    + (d & 31) * 8 + (qq0 & 7);
                bf16x4 v4;
                #pragma unroll
                for (int r = 0; r < 4; ++r) v4[r] = (bf16)acc[i][j][r];
                *(bf16x4*)(vb + off) = v4;
            }
        }
    }
}

// ---------------------------------------------------------------------------
// Split-K MFMA flash attention (R6-exact: 32x32x16, S^T/O^T, glds staging,
// split-2 even slabs, max-subtracted online softmax, launch_bounds(256,3)).
// ---------------------------------------------------------------------------
__global__ __launch_bounds__(256, 3)
void attn_part(const bf16* __restrict__ qb, const bf16* __restrict__ kf,
               const bf16* __restrict__ vf, const float* __restrict__ bias,
               bf16* __restrict__ po, float2* __restrict__ ml)
{
    __shared__ __align__(16) bf16 Ks[2][4096];
    __shared__ __align__(16) bf16 Vs[2][4096];
    __shared__ __align__(16) bf16 Ps[4][32 * 72];

    const int tid  = threadIdx.x;
    const int wv   = tid >> 6, lane = tid & 63;
    const int l31  = lane & 31, b5 = lane >> 5;
    const int x    = blockIdx.x;
    const int bh   = ((x & 7) << 1) | (x >> 3);   // XCD gets same-b head pair
    const int b    = bh >> 3;
    const int qg   = blockIdx.y * 128 + wv * 32 + l31;
    const int ks   = blockIdx.z;

    const bf16* qp = qb + ((size_t)bh * Q_ + qg) * D_;
    bf16x8 bq[4];
    #pragma unroll
    for (int c = 0; c < 4; ++c)
        bq[c] = *(const bf16x8*)(qp + c * 16 + b5 * 8);

    f32x16 acc[2] = {};
    float m_run = -INFINITY, l_run = 0.f;

    const bf16*  kfb  = kf + (size_t)bh * (Q_ * D_) + (size_t)ks * 16 * 4096;
    const bf16*  vfb  = vf + (size_t)bh * (Q_ * D_) + (size_t)ks * 16 * 4096;
    const float* brow = bias + ((size_t)b * Q_ + qg) * Q_ + ks * 1024;

    f32x4 bcur[8], bnxt[8];

    #pragma unroll
    for (int p = 0; p < 2; ++p) {
        gl_lds16(kfb + (wv * 2 + p) * 512 + lane * 8, Ks[0] + (wv * 2 + p) * 512);
        gl_lds16(vfb + (wv * 2 + p) * 512 + lane * 8, Vs[0] + (wv * 2 + p) * 512);
    }
    #pragma unroll
    for (int i = 0; i < 8; ++i)
        bcur[i] = *(const f32x4*)(brow + (i >> 2) * 32 + (i & 3) * 8 + b5 * 4);
    __asm__ volatile("s_waitcnt vmcnt(0)" ::: "memory");
    __syncthreads();

    bf16* pw = Ps[wv] + l31 * 72;

    int cur = 0;
    #pragma unroll 1
    for (int t = 0; t < 16; ++t) {
        if (t < 15) {
            const size_t off = (size_t)(t + 1) * 4096;
            #pragma unroll
            for (int p = 0; p < 2; ++p) {
                gl_lds16(kfb + off + (wv * 2 + p) * 512 + lane * 8,
                         Ks[cur ^ 1] + (wv * 2 + p) * 512);
                gl_lds16(vfb + off + (wv * 2 + p) * 512 + lane * 8,
                         Vs[cur ^ 1] + (wv * 2 + p) * 512);
            }
            const int k0n = (t + 1) * 64;
            #pragma unroll
            for (int i = 0; i < 8; ++i)
                bnxt[i] = *(const f32x4*)(brow + k0n + (i >> 2) * 32 + (i & 3) * 8 + b5 * 4);
        }

        // ---- scores S^T ----
        const bf16* Kc = Ks[cur];
        f32x16 sv[2] = {};
        #pragma unroll
        for (int kg = 0; kg < 2; ++kg)
            #pragma unroll
            for (int c = 0; c < 4; ++c) {
                const bf16x8 ak = *(const bf16x8*)(Kc + kg * 2048 + c * 512 + lane * 8);
                sv[kg] = __builtin_amdgcn_mfma_f32_32x32x16_bf16(ak, bq[c], sv[kg], 0, 0, 0);
            }

        // ---- bias + online softmax (exp2 domain) ----
        float sc[2][16];
        #pragma unroll
        for (int kg = 0; kg < 2; ++kg)
            #pragma unroll
            for (int r = 0; r < 16; ++r)
                sc[kg][r] = fmaf(bcur[kg * 4 + (r >> 2)][r & 3], L2E, sv[kg][r]);

        float tmax = -INFINITY;
        #pragma unroll
        for (int kg = 0; kg < 2; ++kg)
            #pragma unroll
            for (int r = 0; r < 16; ++r)
                tmax = fmaxf(tmax, sc[kg][r]);
        tmax = fmaxf(tmax, __shfl_xor(tmax, 32, 64));

        const float mn = fmaxf(m_run, tmax);
        const float alpha = __builtin_amdgcn_exp2f(m_run - mn);
        m_run = mn;

        float rsum = 0.f;
        #pragma unroll
        for (int kg = 0; kg < 2; ++kg)
            #pragma unroll
            for (int r = 0; r < 16; ++r) {
                sc[kg][r] = __builtin_amdgcn_exp2f(sc[kg][r] - mn);
                rsum += sc[kg][r];
            }
        rsum += __shfl_xor(rsum, 32, 64);
        l_run = l_run * alpha + rsum;
        acc[0] *= alpha;
        acc[1] *= alpha;

        // ---- P^T -> per-wave LDS [q][key] (8x b64) ----
        #pragma unroll
        for (int kg = 0; kg < 2; ++kg)
            #pragma unroll
            for (int gi = 0; gi < 4; ++gi) {
                bf16x4 p4;
                p4[0] = (bf16)sc[kg][gi * 4 + 0];
                p4[1] = (bf16)sc[kg][gi * 4 + 1];
                p4[2] = (bf16)sc[kg][gi * 4 + 2];
                p4[3] = (bf16)sc[kg][gi * 4 + 3];
                *(bf16x4*)(pw + kg * 32 + gi * 8 + b5 * 4) = p4;
            }
        __asm__ volatile("s_waitcnt lgkmcnt(0)" ::: "memory");

        // ---- PV: O^T += V^T * P^T ----
        const bf16* Vc = Vs[cur];
        #pragma unroll
        for (int c4 = 0; c4 < 4; ++c4) {
            const bf16x8 bp = *(const bf16x8*)(pw + c4 * 16 + b5 * 8);
            #pragma unroll
            for (int dg = 0; dg < 2; ++dg) {
                const bf16x8 av = *(const bf16x8*)(Vc + dg * 2048 + c4 * 512 + lane * 8);
                acc[dg] = __builtin_amdgcn_mfma_f32_32x32x16_bf16(av, bp, acc[dg], 0, 0, 0);
            }
        }

        #pragma unroll
        for (int i = 0; i < 8; ++i) bcur[i] = bnxt[i];
        __asm__ volatile("s_waitcnt vmcnt(0)" ::: "memory");
        __syncthreads();
        cur ^= 1;
    }

    // ---- partial epilogue: normalized O (bf16) + (m, l) ----
    const float inv = 1.f / l_run;
    const size_t pbase = ((size_t)(ks * 16 + bh) * Q_ + qg) * 64;
    #pragma unroll
    for (int dg = 0; dg < 2; ++dg)
        #pragma unroll
        for (int gi = 0; gi < 4; ++gi) {
            const int d0 = dg * 32 + gi * 8 + b5 * 4;
            bf16x4 ov;
            #pragma unroll
            for (int r = 0; r < 4; ++r)
                ov[r] = (bf16)(acc[dg][gi * 4 + r] * inv);
            *(bf16x4*)(po + pbase + d0) = ov;
        }
    if (b5 == 0)
        ml[(size_t)(ks * 16 + bh) * Q_ + qg] = make_float2(m_run, l_run);
}

// ---------------------------------------------------------------------------
// Merge 2 split-K partials, apply gate, write gated O in K-PANEL-PACKED
// layout (A-operand of the out-proj GEMM). ogp must NOT alias g.
// ---------------------------------------------------------------------------
__global__ __launch_bounds__(256)
void merge_kernel(const bf16* __restrict__ po, const float2* __restrict__ ml,
                  const bf16* __restrict__ g, bf16* __restrict__ ogp)
{
    const int gid = blockIdx.x * 256 + threadIdx.x;
    const int row = gid >> 3;             // bh*2048 + qg
    const int d8  = (gid & 7) * 8;
    const int bh  = row >> 11, qg = row & 2047;
    const int b   = bh >> 3, h = bh & 7;

    const float2 ml0 = ml[row];
    const float2 ml1 = ml[16 * Q_ + row];
    const float  Mx  = fmaxf(ml0.x, ml1.x);
    const float  w0r = ml0.y * __builtin_amdgcn_exp2f(ml0.x - Mx);
    const float  w1r = ml1.y * __builtin_amdgcn_exp2f(ml1.x - Mx);
    const float  inv = 1.f / (w0r + w1r);
    const float  w0 = w0r * inv, w1 = w1r * inv;

    const bf16x8 o0 = *(const bf16x8*)(po + (size_t)row * 64 + d8);
    const bf16x8 o1 = *(const bf16x8*)(po + (size_t)16 * Q_ * 64 + (size_t)row * 64 + d8);
    const int m = b * Q_ + qg;
    const int n = h * 64 + d8;            // 8 contiguous, within one 32-panel
    const bf16x8 gv = *(const bf16x8*)(g + (size_t)m * 512 + n);
    bf16x8 ov;
    #pragma unroll
    for (int r = 0; r < 8; ++r)
        ov[r] = (bf16)(((float)o0[r] * w0 + (float)o1[r] * w1) * (float)gv[r]);
    *(bf16x8*)(ogp + (size_t)(n >> 5) * (4096 * 32) + (size_t)m * 32 + (n & 31)) = ov;
}

// ---------------------------------------------------------------------------
extern "C" void kernel_launch(void* const* d_in, const int* in_sizes, int n_in,
                              void* d_out, int out_size, void* d_ws, size_t ws_size,
                              hipStream_t stream)
{
    const float* q_x   = (const float*)d_in[0];
    const float* bias  = (const float*)d_in[2];
    const float* w_qkv = (const float*)d_in[3];
    const float* w_o   = (const float*)d_in[4];
    const float* b_o   = (const float*)d_in[5];
    const float* w_g   = (const float*)d_in[6];
    const float* b_g   = (const float*)d_in[7];
    float* out = (float*)d_out;

    char* ws = (char*)d_ws;
    bf16*   po   = (bf16*)(ws);                    // 8 MB partials (overlay, post-GEMM)
    bf16*   qxb  = (bf16*)(ws);                    // 4 MB packed A   (dead before attn)
    bf16*   wcat = (bf16*)(ws + (4u  << 20));      // 2 MB packed W   (dead before attn)
    bf16*   qb   = (bf16*)(ws + (12u << 20));      // 4 MB q [B,H,Q,D]
    bf16*   ogp  = (bf16*)(ws + (12u << 20));      // 4 MB packed gated-O (overlays qb, post-attn)
    bf16*   kb   = (bf16*)(ws + (16u << 20));      // 4 MB K frag-ordered
    bf16*   vb   = (bf16*)(ws + (20u << 20));      // 4 MB V^T frag-ordered
    bf16*   gb   = (bf16*)(ws + (24u << 20));      // 4 MB gate
    bf16*   wob  = (bf16*)(ws + (28u << 20));      // 0.5 MB packed W_o
    float2* ml   = (float2*)(ws + (28u << 20) + (1u << 19));  // 512 KB

    // 1) fp32 -> bf16 conversions into K-panel-packed layouts
    convert_kernel<<<(S0 + S1 + S2 + S3) / (256 * 8), 256, 0, stream>>>(
        q_x, w_qkv, w_g, w_o, qxb, wcat, wob);
    // 2) fused QKV + gate projection (packed staging, contiguous glds)
    gemm_bf16<128, 64, 0, 2048><<<dim3(32, 32), 256, 0, stream>>>(
        qxb, wcat, b_g, nullptr, qb, kb, vb, gb);
    // 3) split-K(2) flash attention partials (R6-exact)
    attn_part<<<dim3(B_ * H_, Q_ / 128, 2), 256, 0, stream>>>(qb, kb, vb, bias, po, ml);
    // 4) merge partials + gate -> packed gated-O (into dead qb region)
    merge_kernel<<<(16 * Q_ * 8) / 256, 256, 0, stream>>>(po, ml, gb, ogp);
    // 5) output projection + b_o (packed staging)
    gemm_bf16<64, 64, 1, 512><<<dim3(64, 8), 256, 0, stream>>>(
        ogp, wob, b_o, out, nullptr, nullptr, nullptr, nullptr);
}